// Round 19
// baseline (1866.263 us; speedup 1.0000x reference)
//
#include <hip/hip_runtime.h>
#include <math.h>

static inline int cdiv(int a, int b) { return (a + b - 1) / b; }

typedef __attribute__((ext_vector_type(8))) short short8v;
typedef __attribute__((ext_vector_type(4))) float f32x4;

__device__ inline unsigned bf16rne(float x) {
  unsigned u = __builtin_bit_cast(unsigned, x);
  return (u + 0x7FFFu + ((u >> 16) & 1u)) >> 16;
}
__device__ inline float bfhi(unsigned h) { return __builtin_bit_cast(float, h << 16); }
// packed pair: hi bf16 in low16, lo bf16 in high16
__device__ inline unsigned pk(float v) {
  unsigned hb = bf16rne(v);
  return hb | (bf16rne(v - bfhi(hb)) << 16);
}

// ---------------- CSR build ----------------
__global__ void k_count(const int* __restrict__ dst, int E, int* __restrict__ cnt) {
  int i = blockIdx.x * 256 + threadIdx.x;
  if (i < E) atomicAdd(&cnt[dst[i]], 1);
}

__global__ __launch_bounds__(256) void k_scan_chunk(const int* __restrict__ in, int n,
                                                    int* __restrict__ out, int* __restrict__ sums) {
  __shared__ int tsum[256];
  int base = blockIdx.x * 1024;
  int t = threadIdx.x;
  int v[4]; int s = 0;
#pragma unroll
  for (int i = 0; i < 4; i++) { int idx = base + t * 4 + i; int x = (idx < n) ? in[idx] : 0; v[i] = x; s += x; }
  tsum[t] = s;
  __syncthreads();
  int x = s;
  for (int off = 1; off < 256; off <<= 1) {
    int y = (t >= off) ? tsum[t - off] : 0;
    __syncthreads();
    x += y;
    tsum[t] = x;
    __syncthreads();
  }
  int run = x - s;
#pragma unroll
  for (int i = 0; i < 4; i++) { int idx = base + t * 4 + i; if (idx < n) out[idx] = run; run += v[i]; }
  if (t == 255 && sums) sums[blockIdx.x] = x;
}

__global__ void k_scan_add(int* __restrict__ out, int n, const int* __restrict__ se,
                           int total, int* __restrict__ cur) {
  int i = blockIdx.x * 256 + threadIdx.x;
  if (i < n) { int v = out[i] + se[i >> 10]; out[i] = v; cur[i] = v; }
  if (i == 0) out[n] = total;
}

// dst-range-binned fill pass: only edges with lo <= dst < hi are placed.
__global__ void k_fillr(const int* __restrict__ src, const int* __restrict__ dst, int E,
                        int* __restrict__ cur, int* __restrict__ adj, int lo, int hi) {
  int i = blockIdx.x * 256 + threadIdx.x;
  if (i < E) {
    int d = dst[i];
    if (d >= lo && d < hi) { int p = atomicAdd(&cur[d], 1); adj[p] = src[i]; }
  }
}

// ---------------- weight pre-pack (tiny, once) ----------------
__global__ void k_w1t_pk(const float* __restrict__ W1, unsigned* __restrict__ o) {
  int i = blockIdx.x * 256 + threadIdx.x;
  if (i < 60840) { int h = i / 6084, r = i % 6084, c = r / 78, k = r % 78;
    o[i] = pk(W1[(size_t)k * 780 + h * 78 + c]); }
}
__global__ void k_w2t_pk(const float* __restrict__ W2, unsigned* __restrict__ o) {
  int i = blockIdx.x * 256 + threadIdx.x;
  if (i < 99840) { int n = i / 780, k = i % 780;
    o[i] = pk(W2[(size_t)k * 128 + n]); }
}

// ---------------- GAT1 attention-logit projections ----------------
__global__ void k_vsrc(const float* __restrict__ W1, const float* __restrict__ a_src,
                       const float* __restrict__ a_dst, float* __restrict__ Vs, float* __restrict__ Vd) {
  int t = blockIdx.x * 64 + threadIdx.x;
  if (t >= 780) return;
  int k = t / 10, h = t % 10;
  float ss = 0.f, sd = 0.f;
  for (int c = 0; c < 78; c++) {
    float w = W1[k * 780 + h * 78 + c];
    ss += w * a_src[h * 78 + c];
    sd += w * a_dst[h * 78 + c];
  }
  Vs[k * 10 + h] = ss; Vd[k * 10 + h] = sd;
}

__global__ void k_alar1(const float* __restrict__ x, const float* __restrict__ Vs,
                        const float* __restrict__ Vd, float* __restrict__ al,
                        float* __restrict__ ar, int nd) {
  int t = blockIdx.x * 256 + threadIdx.x;
  if (t >= nd * 10) return;
  int n = t / 10, h = t % 10;
  const float* xr = x + (size_t)n * 78;
  float sa = 0.f, sd = 0.f;
  for (int k = 0; k < 78; k++) { float xv = xr[k]; sa += xv * Vs[k * 10 + h]; sd += xv * Vd[k * 10 + h]; }
  al[t] = sa; ar[t] = sd;
}

// ---------------- GAT1 aggregation (writes packed u32 z, [row][780]) ----------------
__global__ __launch_bounds__(64) void k_gat_agg1(const float* __restrict__ x, const int* __restrict__ adj,
                                                 const int* __restrict__ roff, const float* __restrict__ al,
                                                 const float* __restrict__ ar, unsigned* __restrict__ zp, int node0) {
  int n = node0 + blockIdx.x;
  int lane = threadIdx.x;
  int rs = roff[n];
  int deg = roff[n + 1] - rs;
  int tot = deg + 1;
  __shared__ float m_s[10], is_s[10], ar_s[10];
  __shared__ float red_s[64];
  __shared__ int src_s[64];
  __shared__ float alpha_s[64][10];
  if (lane < 10) ar_s[lane] = ar[n * 10 + lane];
  __syncthreads();
  int h = lane % 10; int eL = lane / 10;
  float mx = -1e30f;
  if (lane < 60) {
    for (int e = eL; e < tot; e += 6) {
      int s = (e == deg) ? n : adj[rs + e];
      float v = al[s * 10 + h] + ar_s[h];
      v = (v >= 0.f) ? v : 0.2f * v;
      mx = fmaxf(mx, v);
    }
  }
  red_s[lane] = mx;
  __syncthreads();
  if (lane < 10) {
    float m = red_s[lane];
    for (int g = 1; g < 6; g++) m = fmaxf(m, red_s[lane + g * 10]);
    m_s[lane] = m;
  }
  __syncthreads();
  float sm = 0.f;
  if (lane < 60) {
    float m = m_s[h];
    for (int e = eL; e < tot; e += 6) {
      int s = (e == deg) ? n : adj[rs + e];
      float v = al[s * 10 + h] + ar_s[h];
      v = (v >= 0.f) ? v : 0.2f * v;
      sm += __expf(v - m);
    }
  }
  red_s[lane] = sm;
  __syncthreads();
  if (lane < 10) {
    float s = 0.f;
    for (int g = 0; g < 6; g++) s += red_s[lane + g * 10];
    is_s[lane] = 1.f / (s + 1e-16f);
  }
  __syncthreads();
  float zA[10], zB[10];
#pragma unroll
  for (int i = 0; i < 10; i++) { zA[i] = 0.f; zB[i] = 0.f; }
  for (int c0 = 0; c0 < tot; c0 += 64) {
    int csz = (tot - c0 < 64) ? (tot - c0) : 64;
    if (lane < csz) {
      int e = c0 + lane;
      src_s[lane] = (e == deg) ? n : adj[rs + e];
    }
    __syncthreads();
    for (int p = lane; p < csz * 10; p += 64) {
      int e = p / 10; int hh = p % 10;
      int s = src_s[e];
      float v = al[s * 10 + hh] + ar_s[hh];
      v = (v >= 0.f) ? v : 0.2f * v;
      alpha_s[e][hh] = __expf(v - m_s[hh]) * is_s[hh];
    }
    __syncthreads();
    for (int e = 0; e < csz; e++) {
      int s = src_s[e];
      float xa = x[(size_t)s * 78 + lane];
      float xb = (lane < 14) ? x[(size_t)s * 78 + 64 + lane] : 0.f;
#pragma unroll
      for (int hh = 0; hh < 10; hh++) {
        float a = alpha_s[e][hh];
        zA[hh] += a * xa;
        zB[hh] += a * xb;
      }
    }
    __syncthreads();
  }
  unsigned* zr = zp + (size_t)blockIdx.x * 780;
#pragma unroll
  for (int hh = 0; hh < 10; hh++) {
    zr[hh * 78 + lane] = pk(zA[hh]);
    if (lane < 14) zr[hh * 78 + 64 + lane] = pk(zB[hh]);
  }
}

// ---------------- packed-pair bf16 MFMA GEMM ----------------
// C = A @ Bt^T (+bias). A: packed u32 [M][lda]. Bt: packed [N][ldb].
// 3-term split product AhBh + AhBl + AlBh, f32 accumulate.
// blockIdx.y = head (strided by hs*), blockIdx.z = N-tile (bn).
// R17 staging (guarded u32 pair loads) — R18's unguarded uint2+v_perm raised
// FETCH 145->164 MB and cut occupancy 62->52% for a net slowdown.
// MODE 0: C f32 (+bias). MODE 2: elu(acc+bias) packed back in-place at A offsets.
template <int RT, int CT, int MODE>
__global__ __launch_bounds__(256) void k_mfpk(const unsigned* __restrict__ Ap, const unsigned* __restrict__ Btp,
                                              const float* __restrict__ bias, float* __restrict__ C,
                                              unsigned* __restrict__ Op,
                                              int M, int N, int K, int lda, int ldb, int ldc,
                                              int hsA, int hsB, int hsBias) {
  const int BM = RT * 32, BN = CT * 32;
  __shared__ short Ah[BM][40], Al[BM][40], Bh[BN][40], Bl[BN][40];
  size_t aoff = (size_t)blockIdx.y * hsA;
  size_t boff = (size_t)blockIdx.y * hsB;
  if (bias) bias += (size_t)blockIdx.y * hsBias;
  int t = threadIdx.x;
  int bm = blockIdx.x * BM;
  int bn = blockIdx.z * BN;
  int w = t >> 6, l = t & 63;
  int wy = w >> 1, wx = w & 1;
  int lm = l & 15, lk = (l >> 4) * 8;

  f32x4 acc[RT][CT];
#pragma unroll
  for (int i = 0; i < RT; i++)
#pragma unroll
    for (int j = 0; j < CT; j++) acc[i][j] = (f32x4){0.f, 0.f, 0.f, 0.f};

  for (int k0 = 0; k0 < K; k0 += 32) {
    // stage A tile (BM x 32): unpack packed pairs into hi/lo LDS
    for (int i = t; i < BM * 16; i += 256) {
      int m = i >> 4, kp = (i & 15) * 2;
      int gm = bm + m, gk = k0 + kp;
      unsigned w0 = 0, w1 = 0;
      if (gm < M) {
        if (gk < K) w0 = Ap[aoff + (size_t)gm * lda + gk];
        if (gk + 1 < K) w1 = Ap[aoff + (size_t)gm * lda + gk + 1];
      }
      *(unsigned*)&Ah[m][kp] = (w0 & 0xFFFFu) | (w1 << 16);
      *(unsigned*)&Al[m][kp] = (w0 >> 16) | (w1 & 0xFFFF0000u);
    }
    // stage B tile (BN x 32)
    for (int i = t; i < BN * 16; i += 256) {
      int n = i >> 4, kp = (i & 15) * 2;
      int gn = bn + n, gk = k0 + kp;
      unsigned w0 = 0, w1 = 0;
      if (gn < N) {
        if (gk < K) w0 = Btp[boff + (size_t)gn * ldb + gk];
        if (gk + 1 < K) w1 = Btp[boff + (size_t)gn * ldb + gk + 1];
      }
      *(unsigned*)&Bh[n][kp] = (w0 & 0xFFFFu) | (w1 << 16);
      *(unsigned*)&Bl[n][kp] = (w0 >> 16) | (w1 & 0xFFFF0000u);
    }
    __syncthreads();
    short8v bhf[CT], blf[CT];
#pragma unroll
    for (int ct = 0; ct < CT; ct++) {
      int col = wx * (CT * 16) + ct * 16 + lm;
      bhf[ct] = *(const short8v*)&Bh[col][lk];
      blf[ct] = *(const short8v*)&Bl[col][lk];
    }
#pragma unroll
    for (int rt = 0; rt < RT; rt++) {
      int row = wy * (RT * 16) + rt * 16 + lm;
      short8v ah = *(const short8v*)&Ah[row][lk];
      short8v alo = *(const short8v*)&Al[row][lk];
#pragma unroll
      for (int ct = 0; ct < CT; ct++) {
        acc[rt][ct] = __builtin_amdgcn_mfma_f32_16x16x32_bf16(ah, bhf[ct], acc[rt][ct], 0, 0, 0);
        acc[rt][ct] = __builtin_amdgcn_mfma_f32_16x16x32_bf16(ah, blf[ct], acc[rt][ct], 0, 0, 0);
        acc[rt][ct] = __builtin_amdgcn_mfma_f32_16x16x32_bf16(alo, bhf[ct], acc[rt][ct], 0, 0, 0);
      }
    }
    __syncthreads();
  }
  // epilogue: D[row][col], col = lane&15, row = (lane>>4)*4 + r (verified)
#pragma unroll
  for (int rt = 0; rt < RT; rt++) {
#pragma unroll
    for (int r = 0; r < 4; r++) {
      int gm = bm + wy * (RT * 16) + rt * 16 + (l >> 4) * 4 + r;
      if (gm >= M) continue;
#pragma unroll
      for (int ct = 0; ct < CT; ct++) {
        int gn = bn + wx * (CT * 16) + ct * 16 + lm;
        if (gn >= N) continue;
        float v = acc[rt][ct][r] + (bias ? bias[gn] : 0.f);
        if (MODE == 0) {
          C[(size_t)gm * ldc + gn] = v;
        } else {
          v = (v > 0.f) ? v : (__expf(v) - 1.f);
          Op[aoff + (size_t)gm * lda + gn] = pk(v);
        }
      }
    }
  }
}

// ---------------- small-tile f32 GEMM (GCN shapes) ----------------
template <int ACT>
__global__ __launch_bounds__(256) void k_gemm(const float* __restrict__ A, const float* __restrict__ B,
                                              const float* __restrict__ bias, float* __restrict__ C,
                                              int M, int N, int K, int lda, int ldb, int ldc) {
  __shared__ float As[16][68];
  __shared__ float Bs[16][68];
  int tx = threadIdx.x % 16, ty = threadIdx.x / 16;
  int bm = blockIdx.x * 64, bn = blockIdx.y * 64;
  float acc[4][4] = {};
  for (int k0 = 0; k0 < K; k0 += 16) {
    for (int i = threadIdx.x; i < 1024; i += 256) {
      int r = i / 16, kk = i % 16;
      int gm = bm + r, gk = k0 + kk;
      As[kk][r] = (gm < M && gk < K) ? A[(size_t)gm * lda + gk] : 0.f;
    }
    for (int i = threadIdx.x; i < 1024; i += 256) {
      int kk = i / 64, c = i % 64;
      int gk = k0 + kk, gn = bn + c;
      Bs[kk][c] = (gk < K && gn < N) ? B[(size_t)gk * ldb + gn] : 0.f;
    }
    __syncthreads();
#pragma unroll
    for (int kk = 0; kk < 16; kk++) {
      float a[4], b[4];
#pragma unroll
      for (int i = 0; i < 4; i++) a[i] = As[kk][ty * 4 + i];
#pragma unroll
      for (int j = 0; j < 4; j++) b[j] = Bs[kk][tx * 4 + j];
#pragma unroll
      for (int i = 0; i < 4; i++)
#pragma unroll
        for (int j = 0; j < 4; j++) acc[i][j] += a[i] * b[j];
    }
    __syncthreads();
  }
#pragma unroll
  for (int i = 0; i < 4; i++) {
    int gm = bm + ty * 4 + i;
    if (gm >= M) continue;
#pragma unroll
    for (int j = 0; j < 4; j++) {
      int gn = bn + tx * 4 + j;
      if (gn >= N) continue;
      float v = acc[i][j] + (bias ? bias[gn] : 0.f);
      if (ACT == 1) v = fmaxf(v, 0.f);
      else if (ACT == 2) v = (v > 0.f) ? v : (__expf(v) - 1.f);
      C[(size_t)gm * ldc + gn] = v;
    }
  }
}

// ---------------- GAT2 ----------------
__global__ __launch_bounds__(64) void k_alar2(const float* __restrict__ h2, const float* __restrict__ a_src,
                                              const float* __restrict__ a_dst, float* __restrict__ al,
                                              float* __restrict__ ar) {
  int n = blockIdx.x, lane = threadIdx.x;
  float v0 = h2[(size_t)n * 128 + lane], v1 = h2[(size_t)n * 128 + 64 + lane];
  float sa = v0 * a_src[lane] + v1 * a_src[64 + lane];
  float sd = v0 * a_dst[lane] + v1 * a_dst[64 + lane];
#pragma unroll
  for (int o = 32; o; o >>= 1) { sa += __shfl_xor(sa, o); sd += __shfl_xor(sd, o); }
  if (lane == 0) { al[n] = sa; ar[n] = sd; }
}

__global__ __launch_bounds__(64) void k_gat_agg2(const float* __restrict__ h2, const int* __restrict__ adj,
                                                 const int* __restrict__ roff, const float* __restrict__ al,
                                                 const float* __restrict__ ar, const float* __restrict__ b2,
                                                 float* __restrict__ out) {
  int n = blockIdx.x, lane = threadIdx.x;
  int rs = roff[n];
  int deg = roff[n + 1] - rs;
  int tot = deg + 1;
  float arn = ar[n];
  float mx = -1e30f;
  for (int e = lane; e < tot; e += 64) {
    int s = (e == deg) ? n : adj[rs + e];
    float v = al[s] + arn; v = (v >= 0.f) ? v : 0.2f * v;
    mx = fmaxf(mx, v);
  }
#pragma unroll
  for (int o = 32; o; o >>= 1) mx = fmaxf(mx, __shfl_xor(mx, o));
  float sm = 0.f;
  for (int e = lane; e < tot; e += 64) {
    int s = (e == deg) ? n : adj[rs + e];
    float v = al[s] + arn; v = (v >= 0.f) ? v : 0.2f * v;
    sm += __expf(v - mx);
  }
#pragma unroll
  for (int o = 32; o; o >>= 1) sm += __shfl_xor(sm, o);
  float inv = 1.f / (sm + 1e-16f);
  float a0 = 0.f, a1 = 0.f;
  for (int e = 0; e < tot; e++) {
    int s = (e == deg) ? n : adj[rs + e];
    float v = al[s] + arn; v = (v >= 0.f) ? v : 0.2f * v;
    float alpha = __expf(v - mx) * inv;
    a0 += alpha * h2[(size_t)s * 128 + lane];
    a1 += alpha * h2[(size_t)s * 128 + 64 + lane];
  }
  out[(size_t)n * 128 + lane]      = fmaxf(a0 + b2[lane], 0.f);
  out[(size_t)n * 128 + 64 + lane] = fmaxf(a1 + b2[64 + lane], 0.f);
}

// ---------------- GCN (f32, proven path) ----------------
__global__ void k_dis(const int* __restrict__ roff, float* __restrict__ dis, int n) {
  int i = blockIdx.x * 256 + threadIdx.x;
  if (i < n) dis[i] = rsqrtf((float)(roff[i + 1] - roff[i] + 1));
}

__global__ __launch_bounds__(64) void k_gcn_agg(const float* __restrict__ h, const int* __restrict__ adj,
                                                const int* __restrict__ roff, const float* __restrict__ dis,
                                                const float* __restrict__ bias, float* __restrict__ out, int C) {
  int n = blockIdx.x, lane = threadIdx.x;
  int rs = roff[n], re = roff[n + 1];
  float dn = dis[n];
  bool act = lane < C;
  float acc = 0.f;
  for (int e = rs; e < re; e++) {
    int s = adj[e];
    float w = dis[s];
    if (act) acc += w * h[(size_t)s * C + lane];
  }
  if (act) {
    acc += dn * h[(size_t)n * C + lane];
    float v = dn * acc + bias[lane];
    out[(size_t)n * C + lane] = fmaxf(v, 0.f);
  }
}

// ---------------- pooling ----------------
__global__ void k_bounds(const int* __restrict__ batch, int n, int* __restrict__ gstart, int G) {
  int i = blockIdx.x * 256 + threadIdx.x;
  if (i >= n) return;
  int b = batch[i];
  if (i == 0) { for (int g = 0; g <= b; g++) gstart[g] = 0; }
  else { int p = batch[i - 1]; for (int g = p + 1; g <= b; g++) gstart[g] = i; }
  if (i == n - 1) { for (int g = b + 1; g <= G; g++) gstart[g] = n; }
}

// 256 threads = (256/C) node-groups x C channels; LDS cross-group max.
__global__ __launch_bounds__(256) void k_pool(const float* __restrict__ xin, const int* __restrict__ gstart,
                                              float* __restrict__ pool, int C) {
  int g = blockIdx.x; int t = threadIdx.x;
  int groups = 256 / C;
  int grp = t / C, c = t % C;
  __shared__ float red[256];
  int n0 = gstart[g], n1 = gstart[g + 1];
  float m = -3.4e38f;
  for (int i = n0 + grp; i < n1; i += groups) m = fmaxf(m, xin[(size_t)i * C + c]);
  red[t] = m;
  __syncthreads();
  if (grp == 0) {
    for (int q = 1; q < groups; q++) m = fmaxf(m, red[q * C + c]);
    pool[(size_t)g * C + c] = m;
  }
}

// ---------------- fused head ----------------
__global__ __launch_bounds__(256) void k_head(const float* __restrict__ pd, const float* __restrict__ pp,
                                              const float* __restrict__ fcgW, const float* __restrict__ fcgb,
                                              const float* __restrict__ l1W, const float* __restrict__ l1b,
                                              const float* __restrict__ f1W, const float* __restrict__ f1b,
                                              const float* __restrict__ f2W, const float* __restrict__ f2b,
                                              const float* __restrict__ oW, const float* __restrict__ ob,
                                              float* __restrict__ out) {
  int g = blockIdx.x, t = threadIdx.x;
  __shared__ float pds[128], pps[64], xcs[256], t1s[1024];
  __shared__ float red[4];
  if (t < 128) pds[t] = pd[(size_t)g * 128 + t];
  else if (t < 192) pps[t - 128] = pp[(size_t)g * 64 + (t - 128)];
  __syncthreads();
  float a = 0.f;
  if (t < 128) {
#pragma unroll 8
    for (int k = 0; k < 128; k++) a += pds[k] * fcgW[k * 128 + t];
    a = fmaxf(a + fcgb[t], 0.f);
  } else {
    int c = t - 128;
#pragma unroll 8
    for (int k = 0; k < 64; k++) a += pps[k] * l1W[k * 128 + c];
    a = fmaxf(a + l1b[c], 0.f);
  }
  xcs[t] = a;
  __syncthreads();
  float acc0 = 0.f, acc1 = 0.f, acc2 = 0.f, acc3 = 0.f;
#pragma unroll 4
  for (int k = 0; k < 256; k++) {
    float xv = xcs[k];
    const float* rw = f1W + (size_t)k * 1024 + t;
    acc0 += xv * rw[0];
    acc1 += xv * rw[256];
    acc2 += xv * rw[512];
    acc3 += xv * rw[768];
  }
  t1s[t]       = fmaxf(acc0 + f1b[t], 0.f);
  t1s[t + 256] = fmaxf(acc1 + f1b[t + 256], 0.f);
  t1s[t + 512] = fmaxf(acc2 + f1b[t + 512], 0.f);
  t1s[t + 768] = fmaxf(acc3 + f1b[t + 768], 0.f);
  __syncthreads();
  float v = 0.f;
#pragma unroll 8
  for (int k = 0; k < 1024; k++) v += t1s[k] * f2W[k * 256 + t];
  v = fmaxf(v + f2b[t], 0.f);
  float s = v * oW[t];
#pragma unroll
  for (int o = 32; o; o >>= 1) s += __shfl_xor(s, o);
  if ((t & 63) == 0) red[t >> 6] = s;
  __syncthreads();
  if (t == 0) out[g] = red[0] + red[1] + red[2] + red[3] + ob[0];
}

extern "C" void kernel_launch(void* const* d_in, const int* in_sizes, int n_in,
                              void* d_out, int out_size, void* d_ws, size_t ws_size,
                              hipStream_t stream) {
  if (n_in < 28) return;
  const float* x_drug  = (const float*)d_in[0];
  const int*   ei_d    = (const int*)d_in[1];
  const int*   batch_d = (const int*)d_in[2];
  const float* x_prot  = (const float*)d_in[3];
  const int*   ei_p    = (const int*)d_in[4];
  const int*   batch_p = (const int*)d_in[5];
  const float* W1     = (const float*)d_in[6];
  const float* a_src1 = (const float*)d_in[7];
  const float* a_dst1 = (const float*)d_in[8];
  const float* b1     = (const float*)d_in[9];
  const float* W2     = (const float*)d_in[10];
  const float* a_src2 = (const float*)d_in[11];
  const float* a_dst2 = (const float*)d_in[12];
  const float* b2     = (const float*)d_in[13];
  const float* fcgW = (const float*)d_in[14];
  const float* fcgb = (const float*)d_in[15];
  const float* g1W  = (const float*)d_in[16];
  const float* g1b  = (const float*)d_in[17];
  const float* g2W  = (const float*)d_in[18];
  const float* g2b  = (const float*)d_in[19];
  const float* l1W  = (const float*)d_in[20];
  const float* l1b  = (const float*)d_in[21];
  const float* f1W  = (const float*)d_in[22];
  const float* f1b  = (const float*)d_in[23];
  const float* f2W  = (const float*)d_in[24];
  const float* f2b  = (const float*)d_in[25];
  const float* oW   = (const float*)d_in[26];
  const float* ob   = (const float*)d_in[27];

  const int nd = in_sizes[0] / 78, ed = in_sizes[1] / 2;
  const int np = in_sizes[3] / 41, ep = in_sizes[4] / 2;
  const int G = 512;

  char* Bp = (char*)d_ws;
  size_t cap = ws_size;
  auto atop = [&](size_t bytes) -> char* {
    cap = (cap - bytes) & ~(size_t)255;
    return Bp + cap;
  };
  float* pooled_d = (float*)atop((size_t)G * 128 * 4);
  float* pooled_p = (float*)atop((size_t)G * 64 * 4);
  int* gs_d = (int*)atop(513 * 4);
  int* gs_p = (int*)atop(513 * 4);
  unsigned* W1tp = (unsigned*)atop(60840 * 4);
  unsigned* W2tp = (unsigned*)atop(99840 * 4);

  size_t off = 0;
  auto alc = [&](size_t bytes) -> char* {
    char* p = Bp + off;
    off = (off + bytes + 255) & ~(size_t)255;
    return p;
  };

  // one-time weight pre-pack
  k_w1t_pk<<<cdiv(60840, 256), 256, 0, stream>>>(W1, W1tp);
  k_w2t_pk<<<cdiv(99840, 256), 256, 0, stream>>>(W2, W2tp);

  // ================= drug branch =================
  int* cur_d  = (int*)alc((size_t)nd * 4);
  int* roff_d = (int*)alc(((size_t)nd + 1) * 4);
  int* adj_d  = (int*)alc((size_t)ed * 4);
  int* part   = (int*)alc(1024 * 4);
  int* parte  = (int*)alc(1024 * 4);
  float* Vs  = (float*)alc(780 * 4);
  float* Vd  = (float*)alc(780 * 4);
  float* al1 = (float*)alc((size_t)nd * 10 * 4);
  float* ar1 = (float*)alc((size_t)nd * 10 * 4);
  float* al2 = (float*)alc((size_t)nd * 4);
  float* ar2 = (float*)alc((size_t)nd * 4);
  float* h2  = (float*)alc((size_t)nd * 128 * 4);

  // slab region: packed z (u32 [row][780] = 3120 B/row); xd2 overlays slab start
  // (zp dead before agg2 writes xd2; stream-ordered). Full-size slabs.
  size_t remain = (cap > off) ? cap - off : 0;
  size_t xd2_bytes = (size_t)nd * 128 * 4;
  unsigned* zp; float* xd2;
  long long slabCap;
  if (remain >= xd2_bytes + (size_t)128 * 3120) {
    xd2 = (float*)(Bp + off);
    slabCap = (long long)(remain / 3120);
  } else {
    xd2 = (float*)alc(xd2_bytes);
    size_t r2 = (cap > off) ? cap - off : 0;
    slabCap = (long long)(r2 / 3120);
  }
  int slabN = (int)((slabCap < (long long)nd) ? slabCap : (long long)nd);
  slabN &= ~127;
  if (slabN < 128) slabN = 128;
  zp = (unsigned*)(Bp + off);

  hipMemsetAsync(cur_d, 0, (size_t)nd * 4, stream);
  k_count<<<cdiv(ed, 256), 256, 0, stream>>>(ei_d + ed, ed, cur_d);
  int nch = cdiv(nd, 1024);
  k_scan_chunk<<<nch, 256, 0, stream>>>(cur_d, nd, roff_d, part);
  k_scan_chunk<<<1, 256, 0, stream>>>(part, nch, parte, nullptr);
  k_scan_add<<<cdiv(nd, 256), 256, 0, stream>>>(roff_d, nd, parte, ed, cur_d);
  {
    const int NP = 4;
    for (int p = 0; p < NP; p++) {
      int lo = (int)((long long)nd * p / NP);
      int hi = (int)((long long)nd * (p + 1) / NP);
      k_fillr<<<cdiv(ed, 256), 256, 0, stream>>>(ei_d, ei_d + ed, ed, cur_d, adj_d, lo, hi);
    }
  }

  k_vsrc<<<cdiv(780, 64), 64, 0, stream>>>(W1, a_src1, a_dst1, Vs, Vd);
  k_alar1<<<cdiv(nd * 10, 256), 256, 0, stream>>>(x_drug, Vs, Vd, al1, ar1, nd);

  for (int s0 = 0; s0 < nd; s0 += slabN) {
    int sm = ((nd - s0) < slabN) ? (nd - s0) : slabN;
    k_gat_agg1<<<sm, 64, 0, stream>>>(x_drug, adj_d, roff_d, al1, ar1, zp, s0);
    // per-head in-place: z_h = elu(z_h @ W1_h + b1_h), K=78; 64x96 tiles, grid (m,10)
    k_mfpk<2, 3, 2><<<dim3(cdiv(sm, 64), 10, 1), 256, 0, stream>>>(
        zp, W1tp, b1, nullptr, zp, sm, 78, 78, 780, 78, 0, 78, 6084, 78);
    // h2 = xd1 @ W2, K=780; 64x128 tile, single z-pass for N=128
    k_mfpk<2, 4, 0><<<dim3(cdiv(sm, 64), 1, 1), 256, 0, stream>>>(
        zp, W2tp, nullptr, h2 + (size_t)s0 * 128, nullptr,
        sm, 128, 780, 780, 780, 128, 0, 0, 0);
  }
  k_alar2<<<nd, 64, 0, stream>>>(h2, a_src2, a_dst2, al2, ar2);
  k_gat_agg2<<<nd, 64, 0, stream>>>(h2, adj_d, roff_d, al2, ar2, b2, xd2);
  k_bounds<<<cdiv(nd, 256), 256, 0, stream>>>(batch_d, nd, gs_d, G);
  k_pool<<<G, 256, 0, stream>>>(xd2, gs_d, pooled_d, 128);

  // ================= protein branch (f32 GEMM, proven; overlays drug buffers) =================
  off = 0;
  int* cur_p  = (int*)alc((size_t)np * 4);
  int* roff_p = (int*)alc(((size_t)np + 1) * 4);
  int* adj_p  = (int*)alc((size_t)ep * 4);
  int* partp  = (int*)alc(1024 * 4);
  int* partep = (int*)alc(1024 * 4);
  float* dis = (float*)alc((size_t)np * 4);
  float* hp1 = (float*)alc((size_t)np * 41 * 4);
  float* xp1 = (float*)alc((size_t)np * 41 * 4);
  float* hp2 = (float*)alc((size_t)np * 64 * 4);
  // xp2 aliases hp1 and spills into xp1 (both dead when xp2 is written); never touches hp2.
  float* xp2 = hp1;

  hipMemsetAsync(cur_p, 0, (size_t)np * 4, stream);
  k_count<<<cdiv(ep, 256), 256, 0, stream>>>(ei_p + ep, ep, cur_p);
  int nchp = cdiv(np, 1024);
  k_scan_chunk<<<nchp, 256, 0, stream>>>(cur_p, np, roff_p, partp);
  k_scan_chunk<<<1, 256, 0, stream>>>(partp, nchp, partep, nullptr);
  k_scan_add<<<cdiv(np, 256), 256, 0, stream>>>(roff_p, np, partep, ep, cur_p);
  {
    const int NP = 10;
    for (int p = 0; p < NP; p++) {
      int lo = (int)((long long)np * p / NP);
      int hi = (int)((long long)np * (p + 1) / NP);
      k_fillr<<<cdiv(ep, 256), 256, 0, stream>>>(ei_p, ei_p + ep, ep, cur_p, adj_p, lo, hi);
    }
  }
  k_dis<<<cdiv(np, 256), 256, 0, stream>>>(roff_p, dis, np);

  k_gemm<0><<<dim3(cdiv(np, 64), 1), 256, 0, stream>>>(x_prot, g1W, nullptr, hp1, np, 41, 41, 41, 41, 41);
  k_gcn_agg<<<np, 64, 0, stream>>>(hp1, adj_p, roff_p, dis, g1b, xp1, 41);
  k_gemm<0><<<dim3(cdiv(np, 64), 1), 256, 0, stream>>>(xp1, g2W, nullptr, hp2, np, 64, 41, 41, 64, 64);
  k_gcn_agg<<<np, 64, 0, stream>>>(hp2, adj_p, roff_p, dis, g2b, xp2, 64);
  k_bounds<<<cdiv(np, 256), 256, 0, stream>>>(batch_p, np, gs_p, G);
  k_pool<<<G, 256, 0, stream>>>(xp2, gs_p, pooled_p, 64);

  // ================= fused head =================
  k_head<<<G, 256, 0, stream>>>(pooled_d, pooled_p, fcgW, fcgb, l1W, l1b,
                                f1W, f1b, f2W, f2b, oW, ob, (float*)d_out);
}

// Round 20
// 1785.793 us; speedup vs baseline: 1.0451x; 1.0451x over previous
//
#include <hip/hip_runtime.h>
#include <math.h>

static inline int cdiv(int a, int b) { return (a + b - 1) / b; }

typedef __attribute__((ext_vector_type(8))) short short8v;
typedef __attribute__((ext_vector_type(4))) float f32x4;

__device__ inline unsigned bf16rne(float x) {
  unsigned u = __builtin_bit_cast(unsigned, x);
  return (u + 0x7FFFu + ((u >> 16) & 1u)) >> 16;
}
__device__ inline float bfhi(unsigned h) { return __builtin_bit_cast(float, h << 16); }
// packed pair: hi bf16 in low16, lo bf16 in high16
__device__ inline unsigned pk(float v) {
  unsigned hb = bf16rne(v);
  return hb | (bf16rne(v - bfhi(hb)) << 16);
}

// ---------------- CSR build ----------------
__global__ void k_count(const int* __restrict__ dst, int E, int* __restrict__ cnt) {
  int i = blockIdx.x * 256 + threadIdx.x;
  if (i < E) atomicAdd(&cnt[dst[i]], 1);
}

__global__ __launch_bounds__(256) void k_scan_chunk(const int* __restrict__ in, int n,
                                                    int* __restrict__ out, int* __restrict__ sums) {
  __shared__ int tsum[256];
  int base = blockIdx.x * 1024;
  int t = threadIdx.x;
  int v[4]; int s = 0;
#pragma unroll
  for (int i = 0; i < 4; i++) { int idx = base + t * 4 + i; int x = (idx < n) ? in[idx] : 0; v[i] = x; s += x; }
  tsum[t] = s;
  __syncthreads();
  int x = s;
  for (int off = 1; off < 256; off <<= 1) {
    int y = (t >= off) ? tsum[t - off] : 0;
    __syncthreads();
    x += y;
    tsum[t] = x;
    __syncthreads();
  }
  int run = x - s;
#pragma unroll
  for (int i = 0; i < 4; i++) { int idx = base + t * 4 + i; if (idx < n) out[idx] = run; run += v[i]; }
  if (t == 255 && sums) sums[blockIdx.x] = x;
}

__global__ void k_scan_add(int* __restrict__ out, int n, const int* __restrict__ se,
                           int total, int* __restrict__ cur) {
  int i = blockIdx.x * 256 + threadIdx.x;
  if (i < n) { int v = out[i] + se[i >> 10]; out[i] = v; cur[i] = v; }
  if (i == 0) out[n] = total;
}

// dst-range-binned fill pass: only edges with lo <= dst < hi are placed.
__global__ void k_fillr(const int* __restrict__ src, const int* __restrict__ dst, int E,
                        int* __restrict__ cur, int* __restrict__ adj, int lo, int hi) {
  int i = blockIdx.x * 256 + threadIdx.x;
  if (i < E) {
    int d = dst[i];
    if (d >= lo && d < hi) { int p = atomicAdd(&cur[d], 1); adj[p] = src[i]; }
  }
}

// ---------------- weight pre-pack (tiny, once) ----------------
__global__ void k_w1t_pk(const float* __restrict__ W1, unsigned* __restrict__ o) {
  int i = blockIdx.x * 256 + threadIdx.x;
  if (i < 60840) { int h = i / 6084, r = i % 6084, c = r / 78, k = r % 78;
    o[i] = pk(W1[(size_t)k * 780 + h * 78 + c]); }
}
__global__ void k_w2t_pk(const float* __restrict__ W2, unsigned* __restrict__ o) {
  int i = blockIdx.x * 256 + threadIdx.x;
  if (i < 99840) { int n = i / 780, k = i % 780;
    o[i] = pk(W2[(size_t)k * 128 + n]); }
}

// ---------------- GAT1 attention-logit projections ----------------
__global__ void k_vsrc(const float* __restrict__ W1, const float* __restrict__ a_src,
                       const float* __restrict__ a_dst, float* __restrict__ Vs, float* __restrict__ Vd) {
  int t = blockIdx.x * 64 + threadIdx.x;
  if (t >= 780) return;
  int k = t / 10, h = t % 10;
  float ss = 0.f, sd = 0.f;
  for (int c = 0; c < 78; c++) {
    float w = W1[k * 780 + h * 78 + c];
    ss += w * a_src[h * 78 + c];
    sd += w * a_dst[h * 78 + c];
  }
  Vs[k * 10 + h] = ss; Vd[k * 10 + h] = sd;
}

__global__ void k_alar1(const float* __restrict__ x, const float* __restrict__ Vs,
                        const float* __restrict__ Vd, float* __restrict__ al,
                        float* __restrict__ ar, int nd) {
  int t = blockIdx.x * 256 + threadIdx.x;
  if (t >= nd * 10) return;
  int n = t / 10, h = t % 10;
  const float* xr = x + (size_t)n * 78;
  float sa = 0.f, sd = 0.f;
  for (int k = 0; k < 78; k++) { float xv = xr[k]; sa += xv * Vs[k * 10 + h]; sd += xv * Vd[k * 10 + h]; }
  al[t] = sa; ar[t] = sd;
}

// ---------------- GAT1 aggregation (writes packed u32 z, [row][780]) ----------------
__global__ __launch_bounds__(64) void k_gat_agg1(const float* __restrict__ x, const int* __restrict__ adj,
                                                 const int* __restrict__ roff, const float* __restrict__ al,
                                                 const float* __restrict__ ar, unsigned* __restrict__ zp, int node0) {
  int n = node0 + blockIdx.x;
  int lane = threadIdx.x;
  int rs = roff[n];
  int deg = roff[n + 1] - rs;
  int tot = deg + 1;
  __shared__ float m_s[10], is_s[10], ar_s[10];
  __shared__ float red_s[64];
  __shared__ int src_s[64];
  __shared__ float alpha_s[64][10];
  if (lane < 10) ar_s[lane] = ar[n * 10 + lane];
  __syncthreads();
  int h = lane % 10; int eL = lane / 10;
  float mx = -1e30f;
  if (lane < 60) {
    for (int e = eL; e < tot; e += 6) {
      int s = (e == deg) ? n : adj[rs + e];
      float v = al[s * 10 + h] + ar_s[h];
      v = (v >= 0.f) ? v : 0.2f * v;
      mx = fmaxf(mx, v);
    }
  }
  red_s[lane] = mx;
  __syncthreads();
  if (lane < 10) {
    float m = red_s[lane];
    for (int g = 1; g < 6; g++) m = fmaxf(m, red_s[lane + g * 10]);
    m_s[lane] = m;
  }
  __syncthreads();
  float sm = 0.f;
  if (lane < 60) {
    float m = m_s[h];
    for (int e = eL; e < tot; e += 6) {
      int s = (e == deg) ? n : adj[rs + e];
      float v = al[s * 10 + h] + ar_s[h];
      v = (v >= 0.f) ? v : 0.2f * v;
      sm += __expf(v - m);
    }
  }
  red_s[lane] = sm;
  __syncthreads();
  if (lane < 10) {
    float s = 0.f;
    for (int g = 0; g < 6; g++) s += red_s[lane + g * 10];
    is_s[lane] = 1.f / (s + 1e-16f);
  }
  __syncthreads();
  float zA[10], zB[10];
#pragma unroll
  for (int i = 0; i < 10; i++) { zA[i] = 0.f; zB[i] = 0.f; }
  for (int c0 = 0; c0 < tot; c0 += 64) {
    int csz = (tot - c0 < 64) ? (tot - c0) : 64;
    if (lane < csz) {
      int e = c0 + lane;
      src_s[lane] = (e == deg) ? n : adj[rs + e];
    }
    __syncthreads();
    for (int p = lane; p < csz * 10; p += 64) {
      int e = p / 10; int hh = p % 10;
      int s = src_s[e];
      float v = al[s * 10 + hh] + ar_s[hh];
      v = (v >= 0.f) ? v : 0.2f * v;
      alpha_s[e][hh] = __expf(v - m_s[hh]) * is_s[hh];
    }
    __syncthreads();
    for (int e = 0; e < csz; e++) {
      int s = src_s[e];
      float xa = x[(size_t)s * 78 + lane];
      float xb = (lane < 14) ? x[(size_t)s * 78 + 64 + lane] : 0.f;
#pragma unroll
      for (int hh = 0; hh < 10; hh++) {
        float a = alpha_s[e][hh];
        zA[hh] += a * xa;
        zB[hh] += a * xb;
      }
    }
    __syncthreads();
  }
  unsigned* zr = zp + (size_t)blockIdx.x * 780;
#pragma unroll
  for (int hh = 0; hh < 10; hh++) {
    zr[hh * 78 + lane] = pk(zA[hh]);
    if (lane < 14) zr[hh * 78 + 64 + lane] = pk(zB[hh]);
  }
}

// ---------------- packed-pair bf16 MFMA GEMM ----------------
// C = A @ Bt^T (+bias). A: packed u32 [M][lda]. Bt: packed [N][ldb].
// 3-term split product AhBh + AhBl + AlBh, f32 accumulate.
// blockIdx.y = head (strided by hs*), blockIdx.z = N-tile (bn).
// R17-exact: guarded u32 pair staging; W2 as <2,2> z=2 (R18 v_perm and R19
// <2,4> single-pass both regressed ~60-70 us).
// MODE 0: C f32 (+bias). MODE 2: elu(acc+bias) packed back in-place at A offsets.
template <int RT, int CT, int MODE>
__global__ __launch_bounds__(256) void k_mfpk(const unsigned* __restrict__ Ap, const unsigned* __restrict__ Btp,
                                              const float* __restrict__ bias, float* __restrict__ C,
                                              unsigned* __restrict__ Op,
                                              int M, int N, int K, int lda, int ldb, int ldc,
                                              int hsA, int hsB, int hsBias) {
  const int BM = RT * 32, BN = CT * 32;
  __shared__ short Ah[BM][40], Al[BM][40], Bh[BN][40], Bl[BN][40];
  size_t aoff = (size_t)blockIdx.y * hsA;
  size_t boff = (size_t)blockIdx.y * hsB;
  if (bias) bias += (size_t)blockIdx.y * hsBias;
  int t = threadIdx.x;
  int bm = blockIdx.x * BM;
  int bn = blockIdx.z * BN;
  int w = t >> 6, l = t & 63;
  int wy = w >> 1, wx = w & 1;
  int lm = l & 15, lk = (l >> 4) * 8;

  f32x4 acc[RT][CT];
#pragma unroll
  for (int i = 0; i < RT; i++)
#pragma unroll
    for (int j = 0; j < CT; j++) acc[i][j] = (f32x4){0.f, 0.f, 0.f, 0.f};

  for (int k0 = 0; k0 < K; k0 += 32) {
    // stage A tile (BM x 32): unpack packed pairs into hi/lo LDS
    for (int i = t; i < BM * 16; i += 256) {
      int m = i >> 4, kp = (i & 15) * 2;
      int gm = bm + m, gk = k0 + kp;
      unsigned w0 = 0, w1 = 0;
      if (gm < M) {
        if (gk < K) w0 = Ap[aoff + (size_t)gm * lda + gk];
        if (gk + 1 < K) w1 = Ap[aoff + (size_t)gm * lda + gk + 1];
      }
      *(unsigned*)&Ah[m][kp] = (w0 & 0xFFFFu) | (w1 << 16);
      *(unsigned*)&Al[m][kp] = (w0 >> 16) | (w1 & 0xFFFF0000u);
    }
    // stage B tile (BN x 32)
    for (int i = t; i < BN * 16; i += 256) {
      int n = i >> 4, kp = (i & 15) * 2;
      int gn = bn + n, gk = k0 + kp;
      unsigned w0 = 0, w1 = 0;
      if (gn < N) {
        if (gk < K) w0 = Btp[boff + (size_t)gn * ldb + gk];
        if (gk + 1 < K) w1 = Btp[boff + (size_t)gn * ldb + gk + 1];
      }
      *(unsigned*)&Bh[n][kp] = (w0 & 0xFFFFu) | (w1 << 16);
      *(unsigned*)&Bl[n][kp] = (w0 >> 16) | (w1 & 0xFFFF0000u);
    }
    __syncthreads();
    short8v bhf[CT], blf[CT];
#pragma unroll
    for (int ct = 0; ct < CT; ct++) {
      int col = wx * (CT * 16) + ct * 16 + lm;
      bhf[ct] = *(const short8v*)&Bh[col][lk];
      blf[ct] = *(const short8v*)&Bl[col][lk];
    }
#pragma unroll
    for (int rt = 0; rt < RT; rt++) {
      int row = wy * (RT * 16) + rt * 16 + lm;
      short8v ah = *(const short8v*)&Ah[row][lk];
      short8v alo = *(const short8v*)&Al[row][lk];
#pragma unroll
      for (int ct = 0; ct < CT; ct++) {
        acc[rt][ct] = __builtin_amdgcn_mfma_f32_16x16x32_bf16(ah, bhf[ct], acc[rt][ct], 0, 0, 0);
        acc[rt][ct] = __builtin_amdgcn_mfma_f32_16x16x32_bf16(ah, blf[ct], acc[rt][ct], 0, 0, 0);
        acc[rt][ct] = __builtin_amdgcn_mfma_f32_16x16x32_bf16(alo, bhf[ct], acc[rt][ct], 0, 0, 0);
      }
    }
    __syncthreads();
  }
  // epilogue: D[row][col], col = lane&15, row = (lane>>4)*4 + r (verified)
#pragma unroll
  for (int rt = 0; rt < RT; rt++) {
#pragma unroll
    for (int r = 0; r < 4; r++) {
      int gm = bm + wy * (RT * 16) + rt * 16 + (l >> 4) * 4 + r;
      if (gm >= M) continue;
#pragma unroll
      for (int ct = 0; ct < CT; ct++) {
        int gn = bn + wx * (CT * 16) + ct * 16 + lm;
        if (gn >= N) continue;
        float v = acc[rt][ct][r] + (bias ? bias[gn] : 0.f);
        if (MODE == 0) {
          C[(size_t)gm * ldc + gn] = v;
        } else {
          v = (v > 0.f) ? v : (__expf(v) - 1.f);
          Op[aoff + (size_t)gm * lda + gn] = pk(v);
        }
      }
    }
  }
}

// ---------------- small-tile f32 GEMM (GCN shapes) ----------------
template <int ACT>
__global__ __launch_bounds__(256) void k_gemm(const float* __restrict__ A, const float* __restrict__ B,
                                              const float* __restrict__ bias, float* __restrict__ C,
                                              int M, int N, int K, int lda, int ldb, int ldc) {
  __shared__ float As[16][68];
  __shared__ float Bs[16][68];
  int tx = threadIdx.x % 16, ty = threadIdx.x / 16;
  int bm = blockIdx.x * 64, bn = blockIdx.y * 64;
  float acc[4][4] = {};
  for (int k0 = 0; k0 < K; k0 += 16) {
    for (int i = threadIdx.x; i < 1024; i += 256) {
      int r = i / 16, kk = i % 16;
      int gm = bm + r, gk = k0 + kk;
      As[kk][r] = (gm < M && gk < K) ? A[(size_t)gm * lda + gk] : 0.f;
    }
    for (int i = threadIdx.x; i < 1024; i += 256) {
      int kk = i / 64, c = i % 64;
      int gk = k0 + kk, gn = bn + c;
      Bs[kk][c] = (gk < K && gn < N) ? B[(size_t)gk * ldb + gn] : 0.f;
    }
    __syncthreads();
#pragma unroll
    for (int kk = 0; kk < 16; kk++) {
      float a[4], b[4];
#pragma unroll
      for (int i = 0; i < 4; i++) a[i] = As[kk][ty * 4 + i];
#pragma unroll
      for (int j = 0; j < 4; j++) b[j] = Bs[kk][tx * 4 + j];
#pragma unroll
      for (int i = 0; i < 4; i++)
#pragma unroll
        for (int j = 0; j < 4; j++) acc[i][j] += a[i] * b[j];
    }
    __syncthreads();
  }
#pragma unroll
  for (int i = 0; i < 4; i++) {
    int gm = bm + ty * 4 + i;
    if (gm >= M) continue;
#pragma unroll
    for (int j = 0; j < 4; j++) {
      int gn = bn + tx * 4 + j;
      if (gn >= N) continue;
      float v = acc[i][j] + (bias ? bias[gn] : 0.f);
      if (ACT == 1) v = fmaxf(v, 0.f);
      else if (ACT == 2) v = (v > 0.f) ? v : (__expf(v) - 1.f);
      C[(size_t)gm * ldc + gn] = v;
    }
  }
}

// ---------------- GAT2 ----------------
__global__ __launch_bounds__(64) void k_alar2(const float* __restrict__ h2, const float* __restrict__ a_src,
                                              const float* __restrict__ a_dst, float* __restrict__ al,
                                              float* __restrict__ ar) {
  int n = blockIdx.x, lane = threadIdx.x;
  float v0 = h2[(size_t)n * 128 + lane], v1 = h2[(size_t)n * 128 + 64 + lane];
  float sa = v0 * a_src[lane] + v1 * a_src[64 + lane];
  float sd = v0 * a_dst[lane] + v1 * a_dst[64 + lane];
#pragma unroll
  for (int o = 32; o; o >>= 1) { sa += __shfl_xor(sa, o); sd += __shfl_xor(sd, o); }
  if (lane == 0) { al[n] = sa; ar[n] = sd; }
}

__global__ __launch_bounds__(64) void k_gat_agg2(const float* __restrict__ h2, const int* __restrict__ adj,
                                                 const int* __restrict__ roff, const float* __restrict__ al,
                                                 const float* __restrict__ ar, const float* __restrict__ b2,
                                                 float* __restrict__ out) {
  int n = blockIdx.x, lane = threadIdx.x;
  int rs = roff[n];
  int deg = roff[n + 1] - rs;
  int tot = deg + 1;
  float arn = ar[n];
  float mx = -1e30f;
  for (int e = lane; e < tot; e += 64) {
    int s = (e == deg) ? n : adj[rs + e];
    float v = al[s] + arn; v = (v >= 0.f) ? v : 0.2f * v;
    mx = fmaxf(mx, v);
  }
#pragma unroll
  for (int o = 32; o; o >>= 1) mx = fmaxf(mx, __shfl_xor(mx, o));
  float sm = 0.f;
  for (int e = lane; e < tot; e += 64) {
    int s = (e == deg) ? n : adj[rs + e];
    float v = al[s] + arn; v = (v >= 0.f) ? v : 0.2f * v;
    sm += __expf(v - mx);
  }
#pragma unroll
  for (int o = 32; o; o >>= 1) sm += __shfl_xor(sm, o);
  float inv = 1.f / (sm + 1e-16f);
  float a0 = 0.f, a1 = 0.f;
  for (int e = 0; e < tot; e++) {
    int s = (e == deg) ? n : adj[rs + e];
    float v = al[s] + arn; v = (v >= 0.f) ? v : 0.2f * v;
    float alpha = __expf(v - mx) * inv;
    a0 += alpha * h2[(size_t)s * 128 + lane];
    a1 += alpha * h2[(size_t)s * 128 + 64 + lane];
  }
  out[(size_t)n * 128 + lane]      = fmaxf(a0 + b2[lane], 0.f);
  out[(size_t)n * 128 + 64 + lane] = fmaxf(a1 + b2[64 + lane], 0.f);
}

// ---------------- GCN (f32, proven path) ----------------
__global__ void k_dis(const int* __restrict__ roff, float* __restrict__ dis, int n) {
  int i = blockIdx.x * 256 + threadIdx.x;
  if (i < n) dis[i] = rsqrtf((float)(roff[i + 1] - roff[i] + 1));
}

__global__ __launch_bounds__(64) void k_gcn_agg(const float* __restrict__ h, const int* __restrict__ adj,
                                                const int* __restrict__ roff, const float* __restrict__ dis,
                                                const float* __restrict__ bias, float* __restrict__ out, int C) {
  int n = blockIdx.x, lane = threadIdx.x;
  int rs = roff[n], re = roff[n + 1];
  float dn = dis[n];
  bool act = lane < C;
  float acc = 0.f;
  for (int e = rs; e < re; e++) {
    int s = adj[e];
    float w = dis[s];
    if (act) acc += w * h[(size_t)s * C + lane];
  }
  if (act) {
    acc += dn * h[(size_t)n * C + lane];
    float v = dn * acc + bias[lane];
    out[(size_t)n * C + lane] = fmaxf(v, 0.f);
  }
}

// ---------------- pooling ----------------
__global__ void k_bounds(const int* __restrict__ batch, int n, int* __restrict__ gstart, int G) {
  int i = blockIdx.x * 256 + threadIdx.x;
  if (i >= n) return;
  int b = batch[i];
  if (i == 0) { for (int g = 0; g <= b; g++) gstart[g] = 0; }
  else { int p = batch[i - 1]; for (int g = p + 1; g <= b; g++) gstart[g] = i; }
  if (i == n - 1) { for (int g = b + 1; g <= G; g++) gstart[g] = n; }
}

// 256 threads = (256/C) node-groups x C channels; LDS cross-group max.
__global__ __launch_bounds__(256) void k_pool(const float* __restrict__ xin, const int* __restrict__ gstart,
                                              float* __restrict__ pool, int C) {
  int g = blockIdx.x; int t = threadIdx.x;
  int groups = 256 / C;
  int grp = t / C, c = t % C;
  __shared__ float red[256];
  int n0 = gstart[g], n1 = gstart[g + 1];
  float m = -3.4e38f;
  for (int i = n0 + grp; i < n1; i += groups) m = fmaxf(m, xin[(size_t)i * C + c]);
  red[t] = m;
  __syncthreads();
  if (grp == 0) {
    for (int q = 1; q < groups; q++) m = fmaxf(m, red[q * C + c]);
    pool[(size_t)g * C + c] = m;
  }
}

// ---------------- fused head ----------------
__global__ __launch_bounds__(256) void k_head(const float* __restrict__ pd, const float* __restrict__ pp,
                                              const float* __restrict__ fcgW, const float* __restrict__ fcgb,
                                              const float* __restrict__ l1W, const float* __restrict__ l1b,
                                              const float* __restrict__ f1W, const float* __restrict__ f1b,
                                              const float* __restrict__ f2W, const float* __restrict__ f2b,
                                              const float* __restrict__ oW, const float* __restrict__ ob,
                                              float* __restrict__ out) {
  int g = blockIdx.x, t = threadIdx.x;
  __shared__ float pds[128], pps[64], xcs[256], t1s[1024];
  __shared__ float red[4];
  if (t < 128) pds[t] = pd[(size_t)g * 128 + t];
  else if (t < 192) pps[t - 128] = pp[(size_t)g * 64 + (t - 128)];
  __syncthreads();
  float a = 0.f;
  if (t < 128) {
#pragma unroll 8
    for (int k = 0; k < 128; k++) a += pds[k] * fcgW[k * 128 + t];
    a = fmaxf(a + fcgb[t], 0.f);
  } else {
    int c = t - 128;
#pragma unroll 8
    for (int k = 0; k < 64; k++) a += pps[k] * l1W[k * 128 + c];
    a = fmaxf(a + l1b[c], 0.f);
  }
  xcs[t] = a;
  __syncthreads();
  float acc0 = 0.f, acc1 = 0.f, acc2 = 0.f, acc3 = 0.f;
#pragma unroll 4
  for (int k = 0; k < 256; k++) {
    float xv = xcs[k];
    const float* rw = f1W + (size_t)k * 1024 + t;
    acc0 += xv * rw[0];
    acc1 += xv * rw[256];
    acc2 += xv * rw[512];
    acc3 += xv * rw[768];
  }
  t1s[t]       = fmaxf(acc0 + f1b[t], 0.f);
  t1s[t + 256] = fmaxf(acc1 + f1b[t + 256], 0.f);
  t1s[t + 512] = fmaxf(acc2 + f1b[t + 512], 0.f);
  t1s[t + 768] = fmaxf(acc3 + f1b[t + 768], 0.f);
  __syncthreads();
  float v = 0.f;
#pragma unroll 8
  for (int k = 0; k < 1024; k++) v += t1s[k] * f2W[k * 256 + t];
  v = fmaxf(v + f2b[t], 0.f);
  float s = v * oW[t];
#pragma unroll
  for (int o = 32; o; o >>= 1) s += __shfl_xor(s, o);
  if ((t & 63) == 0) red[t >> 6] = s;
  __syncthreads();
  if (t == 0) out[g] = red[0] + red[1] + red[2] + red[3] + ob[0];
}

extern "C" void kernel_launch(void* const* d_in, const int* in_sizes, int n_in,
                              void* d_out, int out_size, void* d_ws, size_t ws_size,
                              hipStream_t stream) {
  if (n_in < 28) return;
  const float* x_drug  = (const float*)d_in[0];
  const int*   ei_d    = (const int*)d_in[1];
  const int*   batch_d = (const int*)d_in[2];
  const float* x_prot  = (const float*)d_in[3];
  const int*   ei_p    = (const int*)d_in[4];
  const int*   batch_p = (const int*)d_in[5];
  const float* W1     = (const float*)d_in[6];
  const float* a_src1 = (const float*)d_in[7];
  const float* a_dst1 = (const float*)d_in[8];
  const float* b1     = (const float*)d_in[9];
  const float* W2     = (const float*)d_in[10];
  const float* a_src2 = (const float*)d_in[11];
  const float* a_dst2 = (const float*)d_in[12];
  const float* b2     = (const float*)d_in[13];
  const float* fcgW = (const float*)d_in[14];
  const float* fcgb = (const float*)d_in[15];
  const float* g1W  = (const float*)d_in[16];
  const float* g1b  = (const float*)d_in[17];
  const float* g2W  = (const float*)d_in[18];
  const float* g2b  = (const float*)d_in[19];
  const float* l1W  = (const float*)d_in[20];
  const float* l1b  = (const float*)d_in[21];
  const float* f1W  = (const float*)d_in[22];
  const float* f1b  = (const float*)d_in[23];
  const float* f2W  = (const float*)d_in[24];
  const float* f2b  = (const float*)d_in[25];
  const float* oW   = (const float*)d_in[26];
  const float* ob   = (const float*)d_in[27];

  const int nd = in_sizes[0] / 78, ed = in_sizes[1] / 2;
  const int np = in_sizes[3] / 41, ep = in_sizes[4] / 2;
  const int G = 512;

  char* Bp = (char*)d_ws;
  size_t cap = ws_size;
  auto atop = [&](size_t bytes) -> char* {
    cap = (cap - bytes) & ~(size_t)255;
    return Bp + cap;
  };
  float* pooled_d = (float*)atop((size_t)G * 128 * 4);
  float* pooled_p = (float*)atop((size_t)G * 64 * 4);
  int* gs_d = (int*)atop(513 * 4);
  int* gs_p = (int*)atop(513 * 4);
  unsigned* W1tp = (unsigned*)atop(60840 * 4);
  unsigned* W2tp = (unsigned*)atop(99840 * 4);

  size_t off = 0;
  auto alc = [&](size_t bytes) -> char* {
    char* p = Bp + off;
    off = (off + bytes + 255) & ~(size_t)255;
    return p;
  };

  // one-time weight pre-pack
  k_w1t_pk<<<cdiv(60840, 256), 256, 0, stream>>>(W1, W1tp);
  k_w2t_pk<<<cdiv(99840, 256), 256, 0, stream>>>(W2, W2tp);

  // ================= drug branch =================
  int* cur_d  = (int*)alc((size_t)nd * 4);
  int* roff_d = (int*)alc(((size_t)nd + 1) * 4);
  int* adj_d  = (int*)alc((size_t)ed * 4);
  int* part   = (int*)alc(1024 * 4);
  int* parte  = (int*)alc(1024 * 4);
  float* Vs  = (float*)alc(780 * 4);
  float* Vd  = (float*)alc(780 * 4);
  float* al1 = (float*)alc((size_t)nd * 10 * 4);
  float* ar1 = (float*)alc((size_t)nd * 10 * 4);
  float* al2 = (float*)alc((size_t)nd * 4);
  float* ar2 = (float*)alc((size_t)nd * 4);
  float* h2  = (float*)alc((size_t)nd * 128 * 4);

  // slab region: packed z (u32 [row][780] = 3120 B/row); xd2 overlays slab start
  // (zp dead before agg2 writes xd2; stream-ordered). Full-size slabs.
  size_t remain = (cap > off) ? cap - off : 0;
  size_t xd2_bytes = (size_t)nd * 128 * 4;
  unsigned* zp; float* xd2;
  long long slabCap;
  if (remain >= xd2_bytes + (size_t)128 * 3120) {
    xd2 = (float*)(Bp + off);
    slabCap = (long long)(remain / 3120);
  } else {
    xd2 = (float*)alc(xd2_bytes);
    size_t r2 = (cap > off) ? cap - off : 0;
    slabCap = (long long)(r2 / 3120);
  }
  int slabN = (int)((slabCap < (long long)nd) ? slabCap : (long long)nd);
  slabN &= ~127;
  if (slabN < 128) slabN = 128;
  zp = (unsigned*)(Bp + off);

  hipMemsetAsync(cur_d, 0, (size_t)nd * 4, stream);
  k_count<<<cdiv(ed, 256), 256, 0, stream>>>(ei_d + ed, ed, cur_d);
  int nch = cdiv(nd, 1024);
  k_scan_chunk<<<nch, 256, 0, stream>>>(cur_d, nd, roff_d, part);
  k_scan_chunk<<<1, 256, 0, stream>>>(part, nch, parte, nullptr);
  k_scan_add<<<cdiv(nd, 256), 256, 0, stream>>>(roff_d, nd, parte, ed, cur_d);
  {
    const int NP = 4;
    for (int p = 0; p < NP; p++) {
      int lo = (int)((long long)nd * p / NP);
      int hi = (int)((long long)nd * (p + 1) / NP);
      k_fillr<<<cdiv(ed, 256), 256, 0, stream>>>(ei_d, ei_d + ed, ed, cur_d, adj_d, lo, hi);
    }
  }

  k_vsrc<<<cdiv(780, 64), 64, 0, stream>>>(W1, a_src1, a_dst1, Vs, Vd);
  k_alar1<<<cdiv(nd * 10, 256), 256, 0, stream>>>(x_drug, Vs, Vd, al1, ar1, nd);

  for (int s0 = 0; s0 < nd; s0 += slabN) {
    int sm = ((nd - s0) < slabN) ? (nd - s0) : slabN;
    k_gat_agg1<<<sm, 64, 0, stream>>>(x_drug, adj_d, roff_d, al1, ar1, zp, s0);
    // per-head in-place: z_h = elu(z_h @ W1_h + b1_h), K=78; 64x96 tiles, grid (m,10)
    k_mfpk<2, 3, 2><<<dim3(cdiv(sm, 64), 10, 1), 256, 0, stream>>>(
        zp, W1tp, b1, nullptr, zp, sm, 78, 78, 780, 78, 0, 78, 6084, 78);
    // h2 = xd1 @ W2, K=780; 64x64 tiles, grid (m,1,2) for N=128
    k_mfpk<2, 2, 0><<<dim3(cdiv(sm, 64), 1, 2), 256, 0, stream>>>(
        zp, W2tp, nullptr, h2 + (size_t)s0 * 128, nullptr,
        sm, 128, 780, 780, 780, 128, 0, 0, 0);
  }
  k_alar2<<<nd, 64, 0, stream>>>(h2, a_src2, a_dst2, al2, ar2);
  k_gat_agg2<<<nd, 64, 0, stream>>>(h2, adj_d, roff_d, al2, ar2, b2, xd2);
  k_bounds<<<cdiv(nd, 256), 256, 0, stream>>>(batch_d, nd, gs_d, G);
  k_pool<<<G, 256, 0, stream>>>(xd2, gs_d, pooled_d, 128);

  // ================= protein branch (f32 GEMM, proven; overlays drug buffers) =================
  off = 0;
  int* cur_p  = (int*)alc((size_t)np * 4);
  int* roff_p = (int*)alc(((size_t)np + 1) * 4);
  int* adj_p  = (int*)alc((size_t)ep * 4);
  int* partp  = (int*)alc(1024 * 4);
  int* partep = (int*)alc(1024 * 4);
  float* dis = (float*)alc((size_t)np * 4);
  float* hp1 = (float*)alc((size_t)np * 41 * 4);
  float* xp1 = (float*)alc((size_t)np * 41 * 4);
  float* hp2 = (float*)alc((size_t)np * 64 * 4);
  // xp2 aliases hp1 and spills into xp1 (both dead when xp2 is written); never touches hp2.
  float* xp2 = hp1;

  hipMemsetAsync(cur_p, 0, (size_t)np * 4, stream);
  k_count<<<cdiv(ep, 256), 256, 0, stream>>>(ei_p + ep, ep, cur_p);
  int nchp = cdiv(np, 1024);
  k_scan_chunk<<<nchp, 256, 0, stream>>>(cur_p, np, roff_p, partp);
  k_scan_chunk<<<1, 256, 0, stream>>>(partp, nchp, partep, nullptr);
  k_scan_add<<<cdiv(np, 256), 256, 0, stream>>>(roff_p, np, partep, ep, cur_p);
  {
    const int NP = 10;
    for (int p = 0; p < NP; p++) {
      int lo = (int)((long long)np * p / NP);
      int hi = (int)((long long)np * (p + 1) / NP);
      k_fillr<<<cdiv(ep, 256), 256, 0, stream>>>(ei_p, ei_p + ep, ep, cur_p, adj_p, lo, hi);
    }
  }
  k_dis<<<cdiv(np, 256), 256, 0, stream>>>(roff_p, dis, np);

  k_gemm<0><<<dim3(cdiv(np, 64), 1), 256, 0, stream>>>(x_prot, g1W, nullptr, hp1, np, 41, 41, 41, 41, 41);
  k_gcn_agg<<<np, 64, 0, stream>>>(hp1, adj_p, roff_p, dis, g1b, xp1, 41);
  k_gemm<0><<<dim3(cdiv(np, 64), 1), 256, 0, stream>>>(xp1, g2W, nullptr, hp2, np, 64, 41, 41, 64, 64);
  k_gcn_agg<<<np, 64, 0, stream>>>(hp2, adj_p, roff_p, dis, g2b, xp2, 64);
  k_bounds<<<cdiv(np, 256), 256, 0, stream>>>(batch_p, np, gs_p, G);
  k_pool<<<G, 256, 0, stream>>>(xp2, gs_p, pooled_p, 64);

  // ================= fused head =================
  k_head<<<G, 256, 0, stream>>>(pooled_d, pooled_p, fcgW, fcgb, l1W, l1b,
                                f1W, f1b, f2W, f2b, oW, ob, (float*)d_out);
}